// Round 3
// baseline (1840.448 us; speedup 1.0000x reference)
//
#include <hip/hip_runtime.h>

#define B_ 32
#define D_ 128
#define T_ 1024
#define K_ 4096
#define NROWS (B_ * T_)   // 32768
#define BM 64             // rows per workgroup
#define BN 128            // codes per k-tile (streamed from L2, not LDS)
#define LP 132            // padded LDS row stride (floats)

struct MI { float m; int i; };

// numpy computes t = a*a elementwise, THEN pairwise-sums (no fma fusion).
__device__ __forceinline__ float opaquef(float x) { asm volatile("" : "+v"(x)); return x; }

// numpy pairwise_sum base case for n=128: 8 accumulators,
// ((r0+r1)+(r2+r3))+((r4+r5)+(r6+r7)). Bit-exact replica.
__device__ float np_sumsq128(const float* a) {
  float r[8];
#pragma unroll
  for (int j = 0; j < 8; ++j) r[j] = opaquef(a[j] * a[j]);
#pragma unroll
  for (int i = 8; i < 128; i += 8) {
#pragma unroll
    for (int j = 0; j < 8; ++j) r[j] = r[j] + opaquef(a[i + j] * a[i + j]);
  }
  return ((r[0] + r[1]) + (r[2] + r[3])) + ((r[4] + r[5]) + (r[6] + r[7]));
}

__global__ void wsq_kernel(const float* __restrict__ W, float* __restrict__ wsq) {
  int k = blockIdx.x * blockDim.x + threadIdx.x;
  if (k < K_) wsq[k] = np_sumsq128(W + (size_t)k * D_);
}

#define FMA8(ii) \
  do { \
    float4 a = av[ii]; \
    _Pragma("unroll") \
    for (int j = 0; j < 8; ++j) { \
      float s = acc[ii][j]; \
      s = __fmaf_rn(a.x, wr[j].x, s); \
      s = __fmaf_rn(a.y, wr[j].y, s); \
      s = __fmaf_rn(a.z, wr[j].z, s); \
      s = __fmaf_rn(a.w, wr[j].w, s); \
      acc[ii][j] = s; \
    } \
  } while (0)

__global__ __launch_bounds__(256, 2) void argmin_kernel(
    const float* __restrict__ x, const float* __restrict__ W,
    const float* __restrict__ wsq, int* __restrict__ qout,
    float* __restrict__ out2) {
  __shared__ float xs[BM][LP];
  __shared__ float xsqs[BM];
  __shared__ MI red[BM][16];
  const int tid = threadIdx.x;
  const int blk = blockIdx.x;
  const int b  = blk / (T_ / BM);
  const int t0 = (blk % (T_ / BM)) * BM;
  const int tx = tid & 15;   // code group: owns 8 consecutive codes per tile
  const int ty = tid >> 4;   // row group: rows ty + 16*i

  // stage x tile: xs[tt][d] = x[b, d, t0+tt]   (coalesced along t)
  {
    int tt = tid & 63;
    int d0 = (tid >> 6) * 32;
    for (int dd = 0; dd < 32; ++dd) {
      int d = d0 + dd;
      xs[tt][d] = x[((size_t)b * D_ + d) * T_ + t0 + tt];
    }
  }
  __syncthreads();
  if (tid < BM) xsqs[tid] = np_sumsq128(&xs[tid][0]);
  __syncthreads();

  float xq[4];
#pragma unroll
  for (int i = 0; i < 4; ++i) xq[i] = xsqs[ty + 16 * i];

  float m1[4];
  int   i1[4];
#pragma unroll
  for (int i = 0; i < 4; ++i) { m1[i] = 3.4e38f; i1[i] = 0x7fffffff; }

  for (int kt = 0; kt < K_ / BN; ++kt) {
    const int c0 = kt * BN;
    const int kbase = c0 + tx * 8;           // this thread's 8 consecutive codes
    const float* wp = W + (size_t)kbase * D_;

    float acc[4][8];
#pragma unroll
    for (int i = 0; i < 4; ++i)
#pragma unroll
      for (int j = 0; j < 8; ++j) acc[i][j] = 0.f;

    float4 wA[8], wB[8], av[4];
#pragma unroll
    for (int j = 0; j < 8; ++j) wA[j] = *(const float4*)&wp[j * D_];

    // 16 steps x 8 d; register double-buffer wA/wB, no barriers, no LDS for W
    for (int s = 0; s < 16; ++s) {
      const int d0 = s * 8;
#pragma unroll
      for (int j = 0; j < 8; ++j) wB[j] = *(const float4*)&wp[j * D_ + d0 + 4];
      {
#pragma unroll
        for (int i = 0; i < 4; ++i) av[i] = *(const float4*)&xs[ty + 16 * i][d0];
        float4* wr = wA;
        FMA8(0); FMA8(1); FMA8(2); FMA8(3);
      }
      if (s < 15) {
#pragma unroll
        for (int j = 0; j < 8; ++j) wA[j] = *(const float4*)&wp[j * D_ + d0 + 8];
      }
      {
#pragma unroll
        for (int i = 0; i < 4; ++i) av[i] = *(const float4*)&xs[ty + 16 * i][d0 + 4];
        float4* wr = wB;
        FMA8(0); FMA8(1); FMA8(2); FMA8(3);
      }
    }

    // epilogue: dist + min, k ascending within thread (j ascending)
    float4 wq0 = *(const float4*)&wsq[kbase];
    float4 wq1 = *(const float4*)&wsq[kbase + 4];
    float wqv[8] = {wq0.x, wq0.y, wq0.z, wq0.w, wq1.x, wq1.y, wq1.z, wq1.w};
#pragma unroll
    for (int j = 0; j < 8; ++j) {
      int k = kbase + j;
#pragma unroll
      for (int i = 0; i < 4; ++i) {
        float t = __fmaf_rn(-2.0f, acc[i][j], wqv[j]);  // RN(wq - 2*mm)
        float v = __fadd_rn(t, xq[i]);                   // quantizing add
        if (v < m1[i]) { m1[i] = v; i1[i] = k; }         // strict < => first occurrence
      }
    }
  }

#pragma unroll
  for (int i = 0; i < 4; ++i) {
    MI t; t.m = m1[i]; t.i = i1[i];
    red[ty + 16 * i][tx] = t;
  }
  __syncthreads();

  if (tid < BM) {
    float M = 3.4e38f;
    int   I = 0x7fffffff;
    for (int j = 0; j < 16; ++j) {
      MI t = red[tid][j];
      if (t.m < M || (t.m == M && t.i < I)) { M = t.m; I = t.i; }
    }
    int rg = b * T_ + t0 + tid;
    qout[rg] = I;
    out2[rg] = (float)I;
  }
}

// out0[r, d] = W[q[r], d]  — coalesced along d
__global__ void scatter0_kernel(const float* __restrict__ W,
                                const int* __restrict__ q,
                                float* __restrict__ out0) {
  int r = blockIdx.x * 2 + (threadIdx.x >> 7);
  int d = threadIdx.x & 127;
  out0[(size_t)r * D_ + d] = W[(size_t)q[r] * D_ + d];
}

// out1[b, d, t] = W[q[b,t], d]  — coalesced along t
__global__ void scatter1_kernel(const float* __restrict__ W,
                                const int* __restrict__ q,
                                float* __restrict__ out1) {
  int b = blockIdx.x >> 7;
  int d = blockIdx.x & 127;
  for (int t = threadIdx.x; t < T_; t += 256) {
    int k = q[b * T_ + t];
    out1[((size_t)b * D_ + d) * T_ + t] = W[(size_t)k * D_ + d];
  }
}

extern "C" void kernel_launch(void* const* d_in, const int* in_sizes, int n_in,
                              void* d_out, int out_size, void* d_ws, size_t ws_size,
                              hipStream_t stream) {
  const float* x = (const float*)d_in[0];
  const float* W = (const float*)d_in[1];
  float* out  = (float*)d_out;
  float* out0 = out;                           // [B,T,D]  4194304
  float* out1 = out + (size_t)NROWS * D_;      // [B,D,T]  4194304
  float* out2 = out + 2 * (size_t)NROWS * D_;  // [B,T]    32768 (as float)

  float* wsq = (float*)d_ws;                              // 16 KB
  int*   q   = (int*)((char*)d_ws + K_ * sizeof(float));  // 128 KB

  wsq_kernel<<<K_ / 256, 256, 0, stream>>>(W, wsq);
  argmin_kernel<<<NROWS / BM, 256, 0, stream>>>(x, W, wsq, q, out2);
  scatter0_kernel<<<NROWS / 2, 256, 0, stream>>>(W, q, out0);
  scatter1_kernel<<<B_ * D_, 256, 0, stream>>>(W, q, out1);
}

// Round 4
// 494.859 us; speedup vs baseline: 3.7191x; 3.7191x over previous
//
#include <hip/hip_runtime.h>

typedef float f4 __attribute__((ext_vector_type(4)));

#define B_ 32
#define D_ 128
#define T_ 1024
#define K_ 4096
#define NROWS (B_ * T_)   // 32768
#define BM 64             // rows per workgroup
#define LPX 132           // padded LDS x row stride (floats)

struct MI { float m; int i; };

// numpy computes t = a*a elementwise, THEN pairwise-sums (no fma fusion).
__device__ __forceinline__ float opaquef(float x) { asm volatile("" : "+v"(x)); return x; }

// numpy pairwise_sum base case for n=128: 8 accumulators,
// ((r0+r1)+(r2+r3))+((r4+r5)+(r6+r7)). Bit-exact replica.
__device__ float np_sumsq128(const float* a) {
  float r[8];
#pragma unroll
  for (int j = 0; j < 8; ++j) r[j] = opaquef(a[j] * a[j]);
#pragma unroll
  for (int i = 8; i < 128; i += 8) {
#pragma unroll
    for (int j = 0; j < 8; ++j) r[j] = r[j] + opaquef(a[i + j] * a[i + j]);
  }
  return ((r[0] + r[1]) + (r[2] + r[3])) + ((r[4] + r[5]) + (r[6] + r[7]));
}

__global__ void wsq_kernel(const float* __restrict__ W, float* __restrict__ wsq) {
  int k = blockIdx.x * blockDim.x + threadIdx.x;
  if (k < K_) wsq[k] = np_sumsq128(W + (size_t)k * D_);
}

// Wt[d][k] = W[k][d]; tile 32x32 via LDS, coalesced both sides.
__global__ void transpose_kernel(const float* __restrict__ W, float* __restrict__ Wt) {
  __shared__ float t[32][33];
  int k0 = blockIdx.x * 32, d0 = blockIdx.y * 32;
  int lx = threadIdx.x & 31, ly = threadIdx.x >> 5;  // 256 thr: ly 0..7
  for (int i = ly; i < 32; i += 8) t[i][lx] = W[(size_t)(k0 + i) * D_ + d0 + lx];
  __syncthreads();
  for (int i = ly; i < 32; i += 8) Wt[(size_t)(d0 + i) * K_ + k0 + lx] = t[lx][i];
}

__global__ __launch_bounds__(256, 2) void argmin_kernel(
    const float* __restrict__ x, const float* __restrict__ Wt,
    const float* __restrict__ wsq, int* __restrict__ qout,
    float* __restrict__ out2) {
  __shared__ float xs[BM][LPX];
  __shared__ float xsqs[BM];
  __shared__ MI red[BM][32];
  const int tid = threadIdx.x;
  const int blk = blockIdx.x;
  const int b  = blk / (T_ / BM);
  const int t0 = (blk % (T_ / BM)) * BM;
  const int tx = tid & 31;   // code group: 4 codes at k0+4tx, 4 at k0+128+4tx
  const int ty = tid >> 5;   // row group: rows ty*8 .. ty*8+7

  // stage x tile: xs[tt][d] = x[b, d, t0+tt]   (coalesced along t)
  {
    int tt = tid & 63;
    int d0 = (tid >> 6) * 32;
    for (int dd = 0; dd < 32; ++dd) {
      int d = d0 + dd;
      xs[tt][d] = x[((size_t)b * D_ + d) * T_ + t0 + tt];
    }
  }
  __syncthreads();
  if (tid < BM) xsqs[tid] = np_sumsq128(&xs[tid][0]);
  __syncthreads();

  float xq[8];
#pragma unroll
  for (int i = 0; i < 8; ++i) xq[i] = xsqs[ty * 8 + i];

  float m1[8];
  int   i1[8];
#pragma unroll
  for (int i = 0; i < 8; ++i) { m1[i] = 3.4e38f; i1[i] = 0x7fffffff; }

  for (int ks = 0; ks < K_ / 256; ++ks) {
    const int k0 = ks * 256;
    const float* wp = Wt + k0 + tx * 4;   // + d*K_ ; second group at +128

    float accA[8][4], accB[8][4];
#pragma unroll
    for (int i = 0; i < 8; ++i)
#pragma unroll
      for (int j = 0; j < 4; ++j) { accA[i][j] = 0.f; accB[i][j] = 0.f; }

    // W double-buffer: prefetch one d4-step ahead (coalesced f4 from L2)
    f4 wa[4], wb[4];
#pragma unroll
    for (int dd = 0; dd < 4; ++dd) {
      wa[dd] = *(const f4*)&wp[(size_t)dd * K_];
      wb[dd] = *(const f4*)&wp[(size_t)dd * K_ + 128];
    }

#pragma unroll 2
    for (int d = 0; d < 128; d += 4) {
      f4 na[4], nb[4];
      if (d < 124) {
#pragma unroll
        for (int dd = 0; dd < 4; ++dd) {
          na[dd] = *(const f4*)&wp[(size_t)(d + 4 + dd) * K_];
          nb[dd] = *(const f4*)&wp[(size_t)(d + 4 + dd) * K_ + 128];
        }
      }
      f4 xv[8];
#pragma unroll
      for (int i = 0; i < 8; ++i) xv[i] = *(const f4*)&xs[ty * 8 + i][d];
#pragma unroll
      for (int i = 0; i < 8; ++i)
#pragma unroll
        for (int j = 0; j < 4; ++j) {
          float sA = accA[i][j], sB = accB[i][j];
#pragma unroll
          for (int dd = 0; dd < 4; ++dd) {   // ascending d: exact chain order
            sA = __fmaf_rn(xv[i][dd], wa[dd][j], sA);
            sB = __fmaf_rn(xv[i][dd], wb[dd][j], sB);
          }
          accA[i][j] = sA; accB[i][j] = sB;
        }
#pragma unroll
      for (int dd = 0; dd < 4; ++dd) { wa[dd] = na[dd]; wb[dd] = nb[dd]; }
    }

    // epilogue: ascending k within thread (A group then B group)
    f4 wqA = *(const f4*)&wsq[k0 + tx * 4];
    f4 wqB = *(const f4*)&wsq[k0 + tx * 4 + 128];
#pragma unroll
    for (int j = 0; j < 4; ++j) {
      int kA = k0 + tx * 4 + j;
#pragma unroll
      for (int i = 0; i < 8; ++i) {
        float t = __fmaf_rn(-2.0f, accA[i][j], wqA[j]);  // RN(wq - 2*mm)
        float v = __fadd_rn(t, xq[i]);                    // quantizing add
        if (v < m1[i]) { m1[i] = v; i1[i] = kA; }
      }
    }
#pragma unroll
    for (int j = 0; j < 4; ++j) {
      int kB = k0 + tx * 4 + 128 + j;
#pragma unroll
      for (int i = 0; i < 8; ++i) {
        float t = __fmaf_rn(-2.0f, accB[i][j], wqB[j]);
        float v = __fadd_rn(t, xq[i]);
        if (v < m1[i]) { m1[i] = v; i1[i] = kB; }
      }
    }
  }

#pragma unroll
  for (int i = 0; i < 8; ++i) {
    MI t; t.m = m1[i]; t.i = i1[i];
    red[ty * 8 + i][tx] = t;
  }
  __syncthreads();

  if (tid < BM) {
    float M = 3.4e38f;
    int   I = 0x7fffffff;
    for (int j = 0; j < 32; ++j) {
      MI t = red[tid][j];
      if (t.m < M || (t.m == M && t.i < I)) { M = t.m; I = t.i; }
    }
    int rg = b * T_ + t0 + tid;
    qout[rg] = I;
    out2[rg] = (float)I;
  }
}

// out0[r, d] = W[q[r], d]  — coalesced along d
__global__ void scatter0_kernel(const float* __restrict__ W,
                                const int* __restrict__ q,
                                float* __restrict__ out0) {
  int r = blockIdx.x * 2 + (threadIdx.x >> 7);
  int d = threadIdx.x & 127;
  out0[(size_t)r * D_ + d] = W[(size_t)q[r] * D_ + d];
}

// out1[b, d, t] = W[q[b,t], d]  — coalesced along t
__global__ void scatter1_kernel(const float* __restrict__ W,
                                const int* __restrict__ q,
                                float* __restrict__ out1) {
  int b = blockIdx.x >> 7;
  int d = blockIdx.x & 127;
  for (int t = threadIdx.x; t < T_; t += 256) {
    int k = q[b * T_ + t];
    out1[((size_t)b * D_ + d) * T_ + t] = W[(size_t)k * D_ + d];
  }
}

extern "C" void kernel_launch(void* const* d_in, const int* in_sizes, int n_in,
                              void* d_out, int out_size, void* d_ws, size_t ws_size,
                              hipStream_t stream) {
  const float* x = (const float*)d_in[0];
  const float* W = (const float*)d_in[1];
  float* out  = (float*)d_out;
  float* out0 = out;                           // [B,T,D]  4194304
  float* out1 = out + (size_t)NROWS * D_;      // [B,D,T]  4194304
  float* out2 = out + 2 * (size_t)NROWS * D_;  // [B,T]    32768 (as float)

  float* wsq = (float*)d_ws;                              // 16 KB
  int*   q   = (int*)((char*)d_ws + K_ * sizeof(float));  // 128 KB
  size_t base = K_ * sizeof(float) + NROWS * sizeof(int);
  // Wt (2 MB): workspace if it fits, else stash in out0 (argmin reads it,
  // scatter0 overwrites it afterwards — stream-ordered, deterministic).
  float* Wt = (ws_size >= base + (size_t)K_ * D_ * sizeof(float))
                  ? (float*)((char*)d_ws + base)
                  : out0;

  wsq_kernel<<<K_ / 256, 256, 0, stream>>>(W, wsq);
  {
    dim3 g(K_ / 32, D_ / 32);
    transpose_kernel<<<g, 256, 0, stream>>>(W, Wt);
  }
  argmin_kernel<<<NROWS / BM, 256, 0, stream>>>(x, Wt, wsq, q, out2);
  scatter0_kernel<<<NROWS / 2, 256, 0, stream>>>(W, q, out0);
  scatter1_kernel<<<B_ * D_, 256, 0, stream>>>(W, q, out1);
}